// Round 7
// baseline (205.768 us; speedup 1.0000x reference)
//
#include <hip/hip_runtime.h>

typedef __bf16 bf16;
using short8 = __attribute__((ext_vector_type(8))) __bf16;
using f32x4  = __attribute__((ext_vector_type(4))) float;

#define N_TOK 4128
#define QD    320
#define DH    40
#define W_VIS 4096
#define SPLITS 4
#define N_SP  4224

#if __has_builtin(__builtin_amdgcn_exp2f)
#define EXP2F(x) __builtin_amdgcn_exp2f(x)
#else
#define EXP2F(x) exp2f(x)
#endif

__device__ __forceinline__ float loadS(const void* b, long i, bool isbf) {
  return isbf ? (float)((const bf16*)b)[i] : ((const float*)b)[i];
}

// ---------- dtype sniffer: att_masks is {0,1}; fp32 -> even halfwords all 0 ----------
__global__ __launch_bounds__(256) void sniff_kernel(const unsigned short* att_h, int* flag) {
  __shared__ int s;
  if (threadIdx.x == 0) s = 0;
  __syncthreads();
  int any = 0;
  for (int i = threadIdx.x; i < 4096; i += 256) any |= (att_h[2 * i] != 0);
  if (any) atomicOr(&s, 1);
  __syncthreads();
  if (threadIdx.x == 0) flag[0] = s;
}

// ---------- prep: weight transposes, x->bf16, mask words (A/B u16), V ones-row ----------
#define SEG_A 102400             /* 409600 weight elems / 4 */
#define SEG_B 330240             /* 1320960 x elems / 4 */
#define SEG_C N_SP
#define SEG_D 33280              /* vswz ones row */
__global__ __launch_bounds__(256) void prep_kernel(
    const void* __restrict__ x, const void* __restrict__ att,
    const void* __restrict__ Wq, const void* __restrict__ Wk,
    const void* __restrict__ Wv, const void* __restrict__ Wo,
    bf16* __restrict__ Wqt, bf16* __restrict__ Wkt,
    bf16* __restrict__ Wvt, bf16* __restrict__ Wot,
    bf16* __restrict__ xbf, unsigned short* __restrict__ awA,
    unsigned short* __restrict__ bwB,
    bf16* __restrict__ vswz, const int* __restrict__ flag) {
  bool isbf = flag[0] != 0;
  int id = blockIdx.x * 256 + threadIdx.x;
  if (id < SEG_A) {                         // weight transpose, 4 n per thread
    int wsel = id / 25600;
    int r = id % 25600;
    int k = r / 80, n4 = (r % 80) * 4;
    const void* src = wsel == 0 ? Wq : wsel == 1 ? Wk : wsel == 2 ? Wv : Wo;
    bf16* dst       = wsel == 0 ? Wqt : wsel == 1 ? Wkt : wsel == 2 ? Wvt : Wot;
    if (!isbf) {
      float4 v = *(const float4*)((const float*)src + k * 320 + n4);
      dst[(n4 + 0) * 320 + k] = (bf16)v.x;
      dst[(n4 + 1) * 320 + k] = (bf16)v.y;
      dst[(n4 + 2) * 320 + k] = (bf16)v.z;
      dst[(n4 + 3) * 320 + k] = (bf16)v.w;
    } else {
#pragma unroll
      for (int i = 0; i < 4; ++i)
        dst[(n4 + i) * 320 + k] = ((const bf16*)src)[k * 320 + n4 + i];
    }
  } else if (id < SEG_A + SEG_B) {          // x -> bf16, 4 elems vectorized
    int i4 = (id - SEG_A) * 4;
    union { short4 s4; bf16 h[4]; } u;
    if (!isbf) {
      float4 v = *(const float4*)((const float*)x + i4);
      u.h[0] = (bf16)v.x; u.h[1] = (bf16)v.y; u.h[2] = (bf16)v.z; u.h[3] = (bf16)v.w;
    } else {
      u.s4 = *(const short4*)((const short*)x + i4);
    }
    *(short4*)(xbf + i4) = u.s4;
  } else if (id < SEG_A + SEG_B + SEG_C) {  // mask words: keep(i,j)=(A[i]&B[j])!=0
    int t = id - (SEG_A + SEG_B);
    unsigned int Aw = 0u, Bw = 0u;
    if (t < N_TOK) {
      unsigned int b9 = 0u; bool forced = false;
      if (t < W_VIS) {
#pragma unroll
        for (int o = 0; o < 8; ++o)
          if (loadS(att, o * W_VIS + t, isbf) != 0.0f) b9 |= (1u << o);
      } else {
        int g = t - W_VIS;
        int rep = g >> 3, oo = g & 7;
        forced = (rep == 1 || rep == 2);
        b9 = 0x100u | (forced ? 0u : (1u << oo));
      }
      Aw = b9 | (forced ? 0x200u : 0u) | 0x400u;
      Bw = b9 | (forced ? 0x400u : 0u) | 0x200u;
    }
    awA[t] = (unsigned short)Aw;
    bwB[t] = (unsigned short)Bw;
  } else {                                   // vswz dt=2 rows d=40..47: ones / zeros
    int t = id - (SEG_A + SEG_B + SEG_C);
    if (t < SEG_D) {
      int li8 = t & 7; int t2 = t >> 3;
      int q = t2 & 3; t2 >>= 2;
      int ksv = t2 & 1; t2 >>= 1;
      int kt = t2 % 65, h = t2 / 65;
      bf16 val = (li8 == 0) ? (bf16)1.0f : (bf16)0.0f;
      short8 v8 = {val, val, val, val, val, val, val, val};
      long base = (((long)h * 65 + kt) * 6 + ksv * 3 + 2) * 512;
      *(short8*)(vswz + base + (q * 16 + 8 + li8) * 8) = v8;
    }
  }
}

// ---------- fused QKV GEMM -> q (row-major, prescaled), kswz/vswz (MFMA-fragment order) ----------
__global__ __launch_bounds__(256) void gemm_qkv(
    const bf16* __restrict__ A,
    const bf16* __restrict__ Bq, const bf16* __restrict__ Bk, const bf16* __restrict__ Bv,
    bf16* __restrict__ q, bf16* __restrict__ kswz, bf16* __restrict__ vswz) {
  const float qscale = 0.15811388300841898f * 1.4426950408889634f;  // scale*log2(e)
  int m0 = blockIdx.x * 64;
  int ng = blockIdx.y * 64;
  int wsel = ng / 320;
  int n_in = ng % 320;
  const bf16* Bt = wsel == 0 ? Bq : wsel == 1 ? Bk : Bv;
  int wv = threadIdx.x >> 6, lane = threadIdx.x & 63;
  int quad = lane >> 4, li = lane & 15;
  int wm = wv >> 1, wn = wv & 1;
  f32x4 acc[2][2];
#pragma unroll
  for (int a = 0; a < 2; a++)
#pragma unroll
    for (int b = 0; b < 2; b++) acc[a][b] = (f32x4){0.f, 0.f, 0.f, 0.f};
#pragma unroll
  for (int ks = 0; ks < 10; ++ks) {
    short8 af[2], bfrag[2];
#pragma unroll
    for (int mt = 0; mt < 2; ++mt) {
      int r = m0 + wm * 32 + mt * 16 + li;
      r = r < N_TOK ? r : N_TOK - 1;
      af[mt] = *(const short8*)(A + r * QD + ks * 32 + quad * 8);
    }
#pragma unroll
    for (int nt = 0; nt < 2; ++nt) {
      int r = n_in + wn * 32 + nt * 16 + li;
      bfrag[nt] = *(const short8*)(Bt + r * QD + ks * 32 + quad * 8);
    }
#pragma unroll
    for (int mt = 0; mt < 2; ++mt)
#pragma unroll
      for (int nt = 0; nt < 2; ++nt)
        acc[mt][nt] = __builtin_amdgcn_mfma_f32_16x16x32_bf16(af[mt], bfrag[nt], acc[mt][nt], 0, 0, 0);
  }
#pragma unroll
  for (int mt = 0; mt < 2; ++mt)
#pragma unroll
    for (int nt = 0; nt < 2; ++nt)
#pragma unroll
      for (int r = 0; r < 4; ++r) {
        int row = m0 + wm * 32 + mt * 16 + quad * 4 + r;
        if (row >= N_TOK) continue;
        int col = n_in + wn * 32 + nt * 16 + li;
        int h = col / DH, d = col % DH;
        float v = acc[mt][nt][r];
        int ktile = row >> 6, rr = row & 63;
        if (wsel == 0) {
          q[h * (N_TOK * DH) + row * DH + d] = (bf16)(v * qscale);
        } else if (wsel == 1) {              // K fragment order
          int nt2 = rr >> 4, li2 = rr & 15;
          long base = (((long)h * 65 + ktile) * 4 + nt2) * 640;
          if (d < 32) kswz[base + ((d >> 3) * 16 + li2) * 8 + (d & 7)] = (bf16)v;
          else        kswz[base + 512 + li2 * 8 + (d - 32)] = (bf16)v;
        } else {                             // V fragment order
          int ksv = rr >> 5, q2 = (rr >> 3) & 3, j2 = rr & 7;
          int dt2 = d >> 4, li2 = d & 15;
          long base = (((long)h * 65 + ktile) * 6 + ksv * 3 + dt2) * 512;
          vswz[base + (q2 * 16 + li2) * 8 + j2] = (bf16)v;
        }
      }
}

// ---------- split-K flash attention: static-max softmax, software-pipelined P ----------
__global__ __launch_bounds__(256) void attn_kernel(
    const bf16* __restrict__ qg, const bf16* __restrict__ kswz, const bf16* __restrict__ vswz,
    const unsigned short* __restrict__ awA, const unsigned short* __restrict__ bwB,
    float* __restrict__ opart, float* __restrict__ lpart) {
  __shared__ unsigned short pbuf[2][4][16][68];   // double-buffered per-wave P tiles
  int bid = blockIdx.x;
  int h = bid & 7;
  int sp = (bid >> 3) & 3;
  int qt = bid >> 5;
  int kt0 = (sp * 65) >> 2;
  int kt1 = ((sp + 1) * 65) >> 2;
  int wv = threadIdx.x >> 6, lane = threadIdx.x & 63;
  int quad = lane >> 4, li = lane & 15;
  const bf16* qh = qg + h * (N_TOK * DH);
  const bf16* kz = kswz + (long)h * 65 * 4 * 640;
  const bf16* vz = vswz + (long)h * 65 * 6 * 512;

  int qrow_base = qt * 64 + wv * 16;
  int qr = qrow_base + li; if (qr > N_TOK - 1) qr = N_TOK - 1;
  short8 qa0 = *(const short8*)(qh + qr * DH + quad * 8);
  short8 qa1 = (quad == 0) ? *(const short8*)(qh + qr * DH + 32) : (short8)(__bf16)0.0f;

  unsigned int aw[4]; int qi[4];
#pragma unroll
  for (int r = 0; r < 4; ++r) {
    qi[r] = qrow_base + quad * 4 + r;
    aw[r] = awA[qi[r]];
  }

  f32x4 o[3];
#pragma unroll
  for (int d = 0; d < 3; ++d) o[d] = (f32x4){0.f, 0.f, 0.f, 0.f};
  const f32x4 cm8 = (f32x4){-8.f, -8.f, -8.f, -8.f};   // static softmax shift
  int dkt = qrow_base >> 6;

  auto qk_tile = [&](int kt, f32x4 s[4], unsigned int bw[4]) {
    const bf16* kb_base = kz + (long)kt * 2560;
#pragma unroll
    for (int nt = 0; nt < 4; ++nt) {
      bw[nt] = bwB[kt * 64 + nt * 16 + li];
      short8 kb0 = *(const short8*)(kb_base + nt * 640 + lane * 8);      // coalesced 1KB
      s[nt] = __builtin_amdgcn_mfma_f32_16x16x32_bf16(qa0, kb0, cm8, 0, 0, 0);
      short8 kb1 = (quad == 0) ? *(const short8*)(kb_base + nt * 640 + 512 + li * 8)
                               : (short8)(__bf16)0.0f;
      s[nt] = __builtin_amdgcn_mfma_f32_16x16x32_bf16(qa1, kb1, s[nt], 0, 0, 0);
    }
  };
  auto exp_write = [&](int kt, int buf, const f32x4 s[4], const unsigned int bw[4]) {
    if (kt == dkt) {
#pragma unroll
      for (int nt = 0; nt < 4; ++nt)
#pragma unroll
        for (int r = 0; r < 4; ++r) {
          bool kp = ((aw[r] & bw[nt]) != 0u) || (qi[r] == (kt * 64 + nt * 16 + li));
          float p = EXP2F(kp ? s[nt][r] : -1e5f);
          pbuf[buf][wv][quad * 4 + r][nt * 16 + li] =
              (unsigned short)(__builtin_bit_cast(unsigned int, p) >> 16);
        }
    } else {
#pragma unroll
      for (int nt = 0; nt < 4; ++nt)
#pragma unroll
        for (int r = 0; r < 4; ++r) {
          bool kp = (aw[r] & bw[nt]) != 0u;
          float p = EXP2F(kp ? s[nt][r] : -1e5f);
          pbuf[buf][wv][quad * 4 + r][nt * 16 + li] =
              (unsigned short)(__builtin_bit_cast(unsigned int, p) >> 16);
        }
    }
  };

  f32x4 s[4]; unsigned int bw[4];
  qk_tile(kt0, s, bw);
  exp_write(kt0, 0, s, bw);
  int cur = 0;
  for (int kt = kt0 + 1; kt < kt1; ++kt) {
    // V frags for the PREVIOUS tile (PV) — issued early for latency slack
    short8 vb[6];
#pragma unroll
    for (int i = 0; i < 6; ++i)
      vb[i] = *(const short8*)(vz + ((long)(kt - 1) * 6 + i) * 512 + lane * 8);
    qk_tile(kt, s, bw);
    // read P(kt-1) BEFORE this tile's writes -> lgkm wait covers only old writes
    union { short8 v; ushort4 u[2]; } fp[2];
#pragma unroll
    for (int ksv = 0; ksv < 2; ++ksv) {
      fp[ksv].u[0] = *(const ushort4*)&pbuf[cur][wv][li][ksv * 32 + quad * 8];
      fp[ksv].u[1] = *(const ushort4*)&pbuf[cur][wv][li][ksv * 32 + quad * 8 + 4];
    }
#pragma unroll
    for (int ksv = 0; ksv < 2; ++ksv)
#pragma unroll
      for (int dt = 0; dt < 3; ++dt)
        o[dt] = __builtin_amdgcn_mfma_f32_16x16x32_bf16(fp[ksv].v, vb[ksv * 3 + dt], o[dt], 0, 0, 0);
    exp_write(kt, cur ^ 1, s, bw);
    cur ^= 1;
  }
  {  // final PV for tile kt1-1
    short8 vb[6];
#pragma unroll
    for (int i = 0; i < 6; ++i)
      vb[i] = *(const short8*)(vz + ((long)(kt1 - 1) * 6 + i) * 512 + lane * 8);
    union { short8 v; ushort4 u[2]; } fp[2];
#pragma unroll
    for (int ksv = 0; ksv < 2; ++ksv) {
      fp[ksv].u[0] = *(const ushort4*)&pbuf[cur][wv][li][ksv * 32 + quad * 8];
      fp[ksv].u[1] = *(const ushort4*)&pbuf[cur][wv][li][ksv * 32 + quad * 8 + 4];
    }
#pragma unroll
    for (int ksv = 0; ksv < 2; ++ksv)
#pragma unroll
      for (int dt = 0; dt < 3; ++dt)
        o[dt] = __builtin_amdgcn_mfma_f32_16x16x32_bf16(fp[ksv].v, vb[ksv * 3 + dt], o[dt], 0, 0, 0);
  }
  long pb2 = (long)(sp * 8 + h) * N_SP;
#pragma unroll
  for (int dt = 0; dt < 3; ++dt) {
    int d = dt * 16 + li;
    if (d < DH) {
#pragma unroll
      for (int r = 0; r < 4; ++r)
        opart[(pb2 + qi[r]) * DH + d] = o[dt][r];
    }
  }
  if (li == 8) {   // vswz dt=2 col d=40 is all-ones -> o[2] is l
#pragma unroll
    for (int r = 0; r < 4; ++r) lpart[pb2 + qi[r]] = o[2][r];
  }
}

// ---------- combine partials across splits (equal weights), float4-vectorized ----------
__global__ __launch_bounds__(256) void combine_kernel(
    const float* __restrict__ opart, const float* __restrict__ lpart,
    bf16* __restrict__ attn) {
  int id = blockIdx.x * 256 + threadIdx.x;   // (h, row, d4): 8*4128*10
  if (id >= 8 * N_TOK * 10) return;
  int d4 = id % 10;
  int rw = (id / 10) % N_TOK;
  int h = id / (10 * N_TOK);
  float4 osum = make_float4(0.f, 0.f, 0.f, 0.f);
  float lsum = 0.f;
#pragma unroll
  for (int s = 0; s < SPLITS; ++s) {
    long rb = (long)(s * 8 + h) * N_SP + rw;
    float4 ov = *(const float4*)(opart + rb * DH + d4 * 4);
    osum.x += ov.x; osum.y += ov.y; osum.z += ov.z; osum.w += ov.w;
    lsum += lpart[rb];
  }
  float rl = 1.0f / fmaxf(lsum, 1e-30f);
  union { short4 s4; bf16 hh[4]; } u;
  u.hh[0] = (bf16)(osum.x * rl); u.hh[1] = (bf16)(osum.y * rl);
  u.hh[2] = (bf16)(osum.z * rl); u.hh[3] = (bf16)(osum.w * rl);
  *(short4*)(attn + rw * QD + h * DH + d4 * 4) = u.s4;
}

// ---------- output projection + bias ----------
__global__ __launch_bounds__(256) void gemm_out(
    const bf16* __restrict__ A, const bf16* __restrict__ Bt,
    const void* __restrict__ bias, void* __restrict__ out,
    const int* __restrict__ flag) {
  bool isbf = flag[0] != 0;
  int m0 = blockIdx.x * 64;
  int n0 = blockIdx.y * 64;
  int wv = threadIdx.x >> 6, lane = threadIdx.x & 63;
  int quad = lane >> 4, li = lane & 15;
  int wm = wv >> 1, wn = wv & 1;
  f32x4 acc[2][2];
#pragma unroll
  for (int a = 0; a < 2; a++)
#pragma unroll
    for (int b = 0; b < 2; b++) acc[a][b] = (f32x4){0.f, 0.f, 0.f, 0.f};
#pragma unroll
  for (int ks = 0; ks < 10; ++ks) {
    short8 af[2], bfrag[2];
#pragma unroll
    for (int mt = 0; mt < 2; ++mt) {
      int r = m0 + wm * 32 + mt * 16 + li;
      r = r < N_TOK ? r : N_TOK - 1;
      af[mt] = *(const short8*)(A + r * QD + ks * 32 + quad * 8);
    }
#pragma unroll
    for (int nt = 0; nt < 2; ++nt) {
      int r = n0 + wn * 32 + nt * 16 + li;
      bfrag[nt] = *(const short8*)(Bt + r * QD + ks * 32 + quad * 8);
    }
#pragma unroll
    for (int mt = 0; mt < 2; ++mt)
#pragma unroll
      for (int nt = 0; nt < 2; ++nt)
        acc[mt][nt] = __builtin_amdgcn_mfma_f32_16x16x32_bf16(af[mt], bfrag[nt], acc[mt][nt], 0, 0, 0);
  }
#pragma unroll
  for (int mt = 0; mt < 2; ++mt)
#pragma unroll
    for (int nt = 0; nt < 2; ++nt)
#pragma unroll
      for (int r = 0; r < 4; ++r) {
        int row = m0 + wm * 32 + mt * 16 + quad * 4 + r;
        if (row >= N_TOK) continue;
        int col = n0 + wn * 32 + nt * 16 + li;
        float val = acc[mt][nt][r] + loadS(bias, col, isbf);
        if (isbf) ((bf16*)out)[row * QD + col] = (bf16)val;
        else      ((float*)out)[row * QD + col] = val;
      }
}

extern "C" void kernel_launch(void* const* d_in, const int* in_sizes, int n_in,
                              void* d_out, int out_size, void* d_ws, size_t ws_size,
                              hipStream_t stream) {
  (void)in_sizes; (void)n_in; (void)out_size; (void)ws_size;
  const void* x   = d_in[0];
  const void* att = d_in[1];
  const void* Wq  = d_in[2];
  const void* Wk  = d_in[3];
  const void* Wv  = d_in[4];
  const void* Wo  = d_in[5];
  const void* bo  = d_in[6];
  char* ws = (char*)d_ws;
  bf16* Wqt = (bf16*)(ws + 0);
  bf16* Wkt = (bf16*)(ws + 204800);
  bf16* Wvt = (bf16*)(ws + 409600);
  bf16* Wot = (bf16*)(ws + 614400);
  unsigned short* awA = (unsigned short*)(ws + 819200);   // 8448
  unsigned short* bwB = (unsigned short*)(ws + 827648);   // 8448 -> 836096
  bf16* xbf  = (bf16*)(ws + 836096);                  // 2641920
  bf16* qb   = (bf16*)(ws + 3478016);                 // 2641920
  bf16* kswz = (bf16*)(ws + 6119936);                 // 8*65*4*1280 = 2662400
  bf16* vswz = (bf16*)(ws + 8782336);                 // 8*65*6*1024 = 3194880
  bf16* attn = (bf16*)(ws + 11977216);                // 2641920
  int* flag  = (int*)(ws + 14619136);                 // 256
  float* opart = (float*)(ws + 14619392);             // 4*8*4224*40*4 = 21626880
  float* lpart = (float*)(ws + 36246272);             // 540672 -> total 36786944

  sniff_kernel<<<1, 256, 0, stream>>>((const unsigned short*)att, flag);
  prep_kernel<<<(SEG_A + SEG_B + SEG_C + SEG_D + 255) / 256, 256, 0, stream>>>(
      x, att, Wq, Wk, Wv, Wo, Wqt, Wkt, Wvt, Wot, xbf, awA, bwB, vswz, flag);
  dim3 g1(65, 15);
  gemm_qkv<<<g1, 256, 0, stream>>>(xbf, Wqt, Wkt, Wvt, qb, kswz, vswz);
  attn_kernel<<<65 * SPLITS * 8, 256, 0, stream>>>(qb, kswz, vswz, awA, bwB, opart, lpart);
  combine_kernel<<<(8 * N_TOK * 10 + 255) / 256, 256, 0, stream>>>(opart, lpart, attn);
  dim3 g2(65, 5);
  gemm_out<<<g2, 256, 0, stream>>>(attn, Wot, bo, d_out, flag);
}

// Round 8
// 197.372 us; speedup vs baseline: 1.0425x; 1.0425x over previous
//
#include <hip/hip_runtime.h>

typedef __bf16 bf16;
using short8 = __attribute__((ext_vector_type(8))) __bf16;
using f32x4  = __attribute__((ext_vector_type(4))) float;

#define N_TOK 4128
#define QD    320
#define DH    40
#define W_VIS 4096
#define SPLITS 4
#define N_SP  4224

#if __has_builtin(__builtin_amdgcn_exp2f)
#define EXP2F(x) __builtin_amdgcn_exp2f(x)
#else
#define EXP2F(x) exp2f(x)
#endif

__device__ __forceinline__ float loadS(const void* b, long i, bool isbf) {
  return isbf ? (float)((const bf16*)b)[i] : ((const float*)b)[i];
}
__device__ __forceinline__ unsigned short bfbits(float x) {
  bf16 h = (bf16)x;
  return __builtin_bit_cast(unsigned short, h);
}

// ---------- dtype sniffer: att_masks is {0,1}; fp32 -> even halfwords all 0 ----------
__global__ __launch_bounds__(256) void sniff_kernel(const unsigned short* att_h, int* flag) {
  __shared__ int s;
  if (threadIdx.x == 0) s = 0;
  __syncthreads();
  int any = 0;
  for (int i = threadIdx.x; i < 4096; i += 256) any |= (att_h[2 * i] != 0);
  if (any) atomicOr(&s, 1);
  __syncthreads();
  if (threadIdx.x == 0) flag[0] = s;
}

// ---------- prep: blocks 0..99 = LDS-tiled weight transpose; rest = x->bf16 + masks ----------
#define SEG_B 330240             /* 1320960 x elems / 4 */
#define SEG_C N_SP
__global__ __launch_bounds__(256) void prep_kernel(
    const void* __restrict__ x, const void* __restrict__ att,
    const void* __restrict__ Wq, const void* __restrict__ Wk,
    const void* __restrict__ Wv, const void* __restrict__ Wo,
    bf16* __restrict__ Wqt, bf16* __restrict__ Wkt,
    bf16* __restrict__ Wvt, bf16* __restrict__ Wot,
    bf16* __restrict__ xbf, unsigned short* __restrict__ awA,
    unsigned short* __restrict__ bwB, const int* __restrict__ flag) {
  __shared__ unsigned short tile[64][68];
  bool isbf = flag[0] != 0;
  if (blockIdx.x < 100) {        // ---- weight transpose: W[k][n] -> Wt[n][k], 64x64 tiles
    int b = blockIdx.x;
    int wsel = b / 25, t5 = b % 25;
    int tr = t5 / 5, tc = t5 % 5;                 // k-tile, n-tile
    const void* src = wsel == 0 ? Wq : wsel == 1 ? Wk : wsel == 2 ? Wv : Wo;
    bf16* dst       = wsel == 0 ? Wqt : wsel == 1 ? Wkt : wsel == 2 ? Wvt : Wot;
    int row = threadIdx.x >> 2;                   // k rel 0..63
    int c16 = (threadIdx.x & 3) * 16;             // n rel start
    long sbase = (long)(tr * 64 + row) * 320 + tc * 64 + c16;
    if (!isbf) {
#pragma unroll
      for (int i = 0; i < 4; ++i) {
        float4 f = *(const float4*)((const float*)src + sbase + i * 4);
        tile[row][c16 + i * 4 + 0] = bfbits(f.x);
        tile[row][c16 + i * 4 + 1] = bfbits(f.y);
        tile[row][c16 + i * 4 + 2] = bfbits(f.z);
        tile[row][c16 + i * 4 + 3] = bfbits(f.w);
      }
    } else {
#pragma unroll
      for (int i = 0; i < 4; ++i) {
        ushort4 s4 = *(const ushort4*)((const unsigned short*)src + sbase + i * 4);
        *(ushort4*)&tile[row][c16 + i * 4] = s4;
      }
    }
    __syncthreads();
    int n = threadIdx.x >> 2;                     // n rel
    int k16 = (threadIdx.x & 3) * 16;             // k rel start
    union { short8 v[2]; unsigned short e[16]; } o;
#pragma unroll
    for (int i = 0; i < 16; ++i) o.e[i] = tile[k16 + i][n];
    bf16* db = dst + (long)(tc * 64 + n) * 320 + tr * 64 + k16;
    *(short8*)db = o.v[0];
    *(short8*)(db + 8) = o.v[1];
    return;
  }
  int id = (blockIdx.x - 100) * 256 + threadIdx.x;
  if (id < SEG_B) {                          // x -> bf16, 4 elems vectorized
    int i4 = id * 4;
    union { short4 s4; unsigned short h[4]; } u;
    if (!isbf) {
      float4 v = *(const float4*)((const float*)x + i4);
      u.h[0] = bfbits(v.x); u.h[1] = bfbits(v.y); u.h[2] = bfbits(v.z); u.h[3] = bfbits(v.w);
    } else {
      u.s4 = *(const short4*)((const short*)x + i4);
    }
    *(short4*)(xbf + i4) = u.s4;
  } else if (id < SEG_B + SEG_C) {           // mask words: keep(i,j)=(A[i]&B[j])!=0
    int t = id - SEG_B;
    unsigned int Aw = 0u, Bw = 0u;
    if (t < N_TOK) {
      unsigned int b9 = 0u; bool forced = false;
      if (t < W_VIS) {
#pragma unroll
        for (int o = 0; o < 8; ++o)
          if (loadS(att, o * W_VIS + t, isbf) != 0.0f) b9 |= (1u << o);
      } else {
        int g = t - W_VIS;
        int rep = g >> 3, oo = g & 7;
        forced = (rep == 1 || rep == 2);
        b9 = 0x100u | (forced ? 0u : (1u << oo));
      }
      Aw = b9 | (forced ? 0x200u : 0u) | 0x400u;
      Bw = b9 | (forced ? 0x400u : 0u) | 0x200u;
    }
    awA[t] = (unsigned short)Aw;
    bwB[t] = (unsigned short)Bw;
  }
}

// ---------- fused QKV GEMM -> q/k/v row-major [h][tok][40] (LDS-staged coalesced epilogue) ----------
__global__ __launch_bounds__(256) void gemm_qkv(
    const bf16* __restrict__ A,
    const bf16* __restrict__ Bq, const bf16* __restrict__ Bk, const bf16* __restrict__ Bv,
    bf16* __restrict__ q, bf16* __restrict__ k, bf16* __restrict__ v) {
  __shared__ unsigned short ct[64][68];
  int m0 = blockIdx.x * 64;
  int ng = blockIdx.y * 64;
  int wsel = ng / 320;                 // 0=q 1=k 2=v (64 | 320 boundaries)
  int n_in = ng % 320;
  const bf16* Bt = wsel == 0 ? Bq : wsel == 1 ? Bk : Bv;
  int wv = threadIdx.x >> 6, lane = threadIdx.x & 63;
  int quad = lane >> 4, li = lane & 15;
  int wm = wv >> 1, wn = wv & 1;
  f32x4 acc[2][2];
#pragma unroll
  for (int a = 0; a < 2; a++)
#pragma unroll
    for (int b = 0; b < 2; b++) acc[a][b] = (f32x4){0.f, 0.f, 0.f, 0.f};
#pragma unroll
  for (int ks = 0; ks < 10; ++ks) {
    short8 af[2], bfrag[2];
#pragma unroll
    for (int mt = 0; mt < 2; ++mt) {
      int r = m0 + wm * 32 + mt * 16 + li;
      r = r < N_TOK ? r : N_TOK - 1;
      af[mt] = *(const short8*)(A + r * QD + ks * 32 + quad * 8);
    }
#pragma unroll
    for (int nt = 0; nt < 2; ++nt) {
      int r = n_in + wn * 32 + nt * 16 + li;
      bfrag[nt] = *(const short8*)(Bt + r * QD + ks * 32 + quad * 8);
    }
#pragma unroll
    for (int mt = 0; mt < 2; ++mt)
#pragma unroll
      for (int nt = 0; nt < 2; ++nt)
        acc[mt][nt] = __builtin_amdgcn_mfma_f32_16x16x32_bf16(af[mt], bfrag[nt], acc[mt][nt], 0, 0, 0);
  }
  const float qscale = (wsel == 0) ? 0.15811388300841898f * 1.4426950408889634f : 1.0f;
  // stage C tile in LDS (row, col) with +4 pad
#pragma unroll
  for (int mt = 0; mt < 2; ++mt)
#pragma unroll
    for (int nt = 0; nt < 2; ++nt)
#pragma unroll
      for (int r = 0; r < 4; ++r) {
        int rr = wm * 32 + mt * 16 + quad * 4 + r;
        int cc = wn * 32 + nt * 16 + li;
        ct[rr][cc] = bfbits(acc[mt][nt][r] * qscale);
      }
  __syncthreads();
  bf16* dst = wsel == 0 ? q : wsel == 1 ? k : v;
  int row = threadIdx.x >> 2, c4 = threadIdx.x & 3;
  int grow = m0 + row;
  if (grow < N_TOK) {
#pragma unroll
    for (int i = 0; i < 4; ++i) {
      int cg = c4 + i * 4;                 // 4-col chunk; 4 | 40 -> never crosses a head
      int col = n_in + cg * 4;
      int h = col / DH, d = col % DH;
      ushort4 pk = *(const ushort4*)&ct[row][cg * 4];
      *(ushort4*)(dst + (long)h * N_TOK * DH + (long)grow * DH + d) = pk;
    }
  }
}

// ---------- swizzle builder: kswz (16B<->16B copies) + vswz (gather) + ones-row ----------
#define KUNITS 166400            /* 8h*65kt*4nt2*80 short8 units */
#define VUNITS 199680            /* 8h*65kt*2ksv*3dt*64 short8 units */
__global__ __launch_bounds__(256) void swz_kernel(
    const bf16* __restrict__ k, const bf16* __restrict__ v,
    bf16* __restrict__ kswz, bf16* __restrict__ vswz) {
  int u = blockIdx.x * 256 + threadIdx.x;
  if (u < KUNITS) {
    int idx8 = u % 80; int t = u / 80;
    int nt2 = t & 3; t >>= 2;
    int kt = t % 65, h = t / 65;
    int li2, soff, doff;
    if (idx8 < 64) { int c = idx8 >> 4; li2 = idx8 & 15; soff = c * 8; doff = idx8 * 8; }
    else           { li2 = idx8 - 64; soff = 32; doff = 512 + li2 * 8; }
    int tok = kt * 64 + nt2 * 16 + li2; if (tok > N_TOK - 1) tok = N_TOK - 1;
    short8 val = *(const short8*)(k + ((long)h * N_TOK + tok) * DH + soff);
    *(short8*)(kswz + (((long)h * 65 + kt) * 4 + nt2) * 640 + doff) = val;
  } else if (u < KUNITS + VUNITS) {
    int w = u - KUNITS;
    int li2 = w & 15; w >>= 4;
    int q2 = w & 3; w >>= 2;
    int dt = w % 3; w /= 3;
    int ksv = w & 1; w >>= 1;
    int kt = w % 65, h = w / 65;
    int d = dt * 16 + li2;
    union { short8 v8; bf16 e[8]; } o;
    int tokb = kt * 64 + ksv * 32 + q2 * 8;
#pragma unroll
    for (int j = 0; j < 8; ++j) {
      int tok = tokb + j; if (tok > N_TOK - 1) tok = N_TOK - 1;
      o.e[j] = (d < DH) ? v[((long)h * N_TOK + tok) * DH + d]
                        : (bf16)(d == DH ? 1.0f : 0.0f);   // d=40 ones-row (l via MFMA)
    }
    *(short8*)(vswz + (((long)h * 65 + kt) * 6 + ksv * 3 + dt) * 512 + (q2 * 16 + li2) * 8) = o.v8;
  }
}

// ---------- split-K flash attention: static-max softmax (R6 structure, u16 masks) ----------
__global__ __launch_bounds__(256) void attn_kernel(
    const bf16* __restrict__ qg, const bf16* __restrict__ kswz, const bf16* __restrict__ vswz,
    const unsigned short* __restrict__ awA, const unsigned short* __restrict__ bwB,
    float* __restrict__ opart, float* __restrict__ lpart) {
  __shared__ unsigned short pbuf[4][16][68];   // per-wave 16x64 P tile (stride 68: 0 conflicts)
  int bid = blockIdx.x;
  int h = bid & 7;
  int sp = (bid >> 3) & 3;
  int qt = bid >> 5;                // 0..64
  int kt0 = (sp * 65) >> 2;
  int kt1 = ((sp + 1) * 65) >> 2;
  int wv = threadIdx.x >> 6, lane = threadIdx.x & 63;
  int quad = lane >> 4, li = lane & 15;
  const bf16* qh = qg + h * (N_TOK * DH);
  const bf16* kz = kswz + (long)h * 65 * 4 * 640;
  const bf16* vz = vswz + (long)h * 65 * 6 * 512;

  int qrow_base = qt * 64 + wv * 16;
  int qr = qrow_base + li; if (qr > N_TOK - 1) qr = N_TOK - 1;
  short8 qa0 = *(const short8*)(qh + qr * DH + quad * 8);
  short8 qa1 = (quad == 0) ? *(const short8*)(qh + qr * DH + 32) : (short8)(__bf16)0.0f;

  unsigned int aw[4]; int qi[4];
#pragma unroll
  for (int r = 0; r < 4; ++r) {
    qi[r] = qrow_base + quad * 4 + r;
    aw[r] = awA[qi[r]];
  }

  f32x4 o[3];
#pragma unroll
  for (int d = 0; d < 3; ++d) o[d] = (f32x4){0.f, 0.f, 0.f, 0.f};
  const f32x4 cm8 = (f32x4){-8.f, -8.f, -8.f, -8.f};   // static softmax shift
  int dkt = qrow_base >> 6;

  for (int kt = kt0; kt < kt1; ++kt) {
    const bf16* kb_base = kz + (long)kt * 2560;
    f32x4 s[4];
    unsigned int bw[4];
#pragma unroll
    for (int nt = 0; nt < 4; ++nt) {
      bw[nt] = bwB[kt * 64 + nt * 16 + li];
      short8 kb0 = *(const short8*)(kb_base + nt * 640 + lane * 8);       // coalesced 1KB
      s[nt] = __builtin_amdgcn_mfma_f32_16x16x32_bf16(qa0, kb0, cm8, 0, 0, 0);
      short8 kb1 = (quad == 0) ? *(const short8*)(kb_base + nt * 640 + 512 + li * 8)
                               : (short8)(__bf16)0.0f;
      s[nt] = __builtin_amdgcn_mfma_f32_16x16x32_bf16(qa1, kb1, s[nt], 0, 0, 0);
    }
    // hoist V fragments (independent of P) so their latency hides under exp phase
    short8 vb[2][3];
#pragma unroll
    for (int ksv = 0; ksv < 2; ++ksv)
#pragma unroll
      for (int dt = 0; dt < 3; ++dt)
        vb[ksv][dt] = *(const short8*)(vz + ((long)kt * 6 + ksv * 3 + dt) * 512 + lane * 8);
    // mask -> exp2 (native) -> truncation-pack bf16 -> LDS
    if (kt == dkt) {
#pragma unroll
      for (int nt = 0; nt < 4; ++nt)
#pragma unroll
        for (int r = 0; r < 4; ++r) {
          bool kp = ((aw[r] & bw[nt]) != 0u) || (qi[r] == (kt * 64 + nt * 16 + li));
          float p = EXP2F(kp ? s[nt][r] : -1e5f);
          pbuf[wv][quad * 4 + r][nt * 16 + li] =
              (unsigned short)(__builtin_bit_cast(unsigned int, p) >> 16);
        }
    } else {
#pragma unroll
      for (int nt = 0; nt < 4; ++nt)
#pragma unroll
        for (int r = 0; r < 4; ++r) {
          bool kp = (aw[r] & bw[nt]) != 0u;
          float p = EXP2F(kp ? s[nt][r] : -1e5f);
          pbuf[wv][quad * 4 + r][nt * 16 + li] =
              (unsigned short)(__builtin_bit_cast(unsigned int, p) >> 16);
        }
    }
    // PV: P (A-layout, own wave's LDS region; compiler inserts lgkmcnt) x V fragments.
    // vswz dt=2 col d=40 is all-ones -> o[2] lane li==8 accumulates l for free.
#pragma unroll
    for (int ksv = 0; ksv < 2; ++ksv) {
      union { short8 v; ushort4 u[2]; } fp;
      fp.u[0] = *(const ushort4*)&pbuf[wv][li][ksv * 32 + quad * 8];
      fp.u[1] = *(const ushort4*)&pbuf[wv][li][ksv * 32 + quad * 8 + 4];
#pragma unroll
      for (int dt = 0; dt < 3; ++dt)
        o[dt] = __builtin_amdgcn_mfma_f32_16x16x32_bf16(fp.v, vb[ksv][dt], o[dt], 0, 0, 0);
    }
  }
  long pb2 = (long)(sp * 8 + h) * N_SP;
#pragma unroll
  for (int dt = 0; dt < 3; ++dt) {
    int d = dt * 16 + li;
    if (d < DH) {
#pragma unroll
      for (int r = 0; r < 4; ++r)
        opart[(pb2 + qi[r]) * DH + d] = o[dt][r];
    }
  }
  if (li == 8) {
#pragma unroll
    for (int r = 0; r < 4; ++r) lpart[pb2 + qi[r]] = o[2][r];
  }
}

// ---------- combine partials across splits (equal weights), float4-vectorized ----------
__global__ __launch_bounds__(256) void combine_kernel(
    const float* __restrict__ opart, const float* __restrict__ lpart,
    bf16* __restrict__ attn) {
  int id = blockIdx.x * 256 + threadIdx.x;   // (h, row, d4): 8*4128*10
  if (id >= 8 * N_TOK * 10) return;
  int d4 = id % 10;
  int rw = (id / 10) % N_TOK;
  int h = id / (10 * N_TOK);
  float4 osum = make_float4(0.f, 0.f, 0.f, 0.f);
  float lsum = 0.f;
#pragma unroll
  for (int s = 0; s < SPLITS; ++s) {
    long rb = (long)(s * 8 + h) * N_SP + rw;
    float4 ov = *(const float4*)(opart + rb * DH + d4 * 4);
    osum.x += ov.x; osum.y += ov.y; osum.z += ov.z; osum.w += ov.w;
    lsum += lpart[rb];
  }
  float rl = 1.0f / fmaxf(lsum, 1e-30f);
  union { short4 s4; unsigned short hh[4]; } u;
  u.hh[0] = bfbits(osum.x * rl); u.hh[1] = bfbits(osum.y * rl);
  u.hh[2] = bfbits(osum.z * rl); u.hh[3] = bfbits(osum.w * rl);
  *(short4*)(attn + rw * QD + h * DH + d4 * 4) = u.s4;
}

// ---------- output projection + bias ----------
__global__ __launch_bounds__(256) void gemm_out(
    const bf16* __restrict__ A, const bf16* __restrict__ Bt,
    const void* __restrict__ bias, void* __restrict__ out,
    const int* __restrict__ flag) {
  bool isbf = flag[0] != 0;
  int m0 = blockIdx.x * 64;
  int n0 = blockIdx.y * 64;
  int wv = threadIdx.x >> 6, lane = threadIdx.x & 63;
  int quad = lane >> 4, li = lane & 15;
  int wm = wv >> 1, wn = wv & 1;
  f32x4 acc[2][2];
#pragma unroll
  for (int a = 0; a < 2; a++)
#pragma unroll
    for (int b = 0; b < 2; b++) acc[a][b] = (f32x4){0.f, 0.f, 0.f, 0.f};
#pragma unroll
  for (int ks = 0; ks < 10; ++ks) {
    short8 af[2], bfrag[2];
#pragma unroll
    for (int mt = 0; mt < 2; ++mt) {
      int r = m0 + wm * 32 + mt * 16 + li;
      r = r < N_TOK ? r : N_TOK - 1;
      af[mt] = *(const short8*)(A + r * QD + ks * 32 + quad * 8);
    }
#pragma unroll
    for (int nt = 0; nt < 2; ++nt) {
      int r = n0 + wn * 32 + nt * 16 + li;
      bfrag[nt] = *(const short8*)(Bt + r * QD + ks * 32 + quad * 8);
    }
#pragma unroll
    for (int mt = 0; mt < 2; ++mt)
#pragma unroll
      for (int nt = 0; nt < 2; ++nt)
        acc[mt][nt] = __builtin_amdgcn_mfma_f32_16x16x32_bf16(af[mt], bfrag[nt], acc[mt][nt], 0, 0, 0);
  }
#pragma unroll
  for (int mt = 0; mt < 2; ++mt)
#pragma unroll
    for (int nt = 0; nt < 2; ++nt)
#pragma unroll
      for (int r = 0; r < 4; ++r) {
        int row = m0 + wm * 32 + mt * 16 + quad * 4 + r;
        if (row >= N_TOK) continue;
        int col = n0 + wn * 32 + nt * 16 + li;
        float val = acc[mt][nt][r] + loadS(bias, col, isbf);
        if (isbf) ((bf16*)out)[row * QD + col] = (bf16)val;
        else      ((float*)out)[row * QD + col] = val;
      }
}

extern "C" void kernel_launch(void* const* d_in, const int* in_sizes, int n_in,
                              void* d_out, int out_size, void* d_ws, size_t ws_size,
                              hipStream_t stream) {
  (void)in_sizes; (void)n_in; (void)out_size; (void)ws_size;
  const void* x   = d_in[0];
  const void* att = d_in[1];
  const void* Wq  = d_in[2];
  const void* Wk  = d_in[3];
  const void* Wv  = d_in[4];
  const void* Wo  = d_in[5];
  const void* bo  = d_in[6];
  char* ws = (char*)d_ws;
  bf16* Wqt = (bf16*)(ws + 0);
  bf16* Wkt = (bf16*)(ws + 204800);
  bf16* Wvt = (bf16*)(ws + 409600);
  bf16* Wot = (bf16*)(ws + 614400);
  unsigned short* awA = (unsigned short*)(ws + 819200);   // 8448
  unsigned short* bwB = (unsigned short*)(ws + 827648);   // 8448 -> 836096
  // aliased unions (stream-ordered lifetimes):
  bf16* xbf  = (bf16*)(ws + 836096);                  // dead after gemm_qkv
  bf16* kswz = (bf16*)(ws + 836096);                  // written by swz (after qkv) 2662400
  bf16* qb   = (bf16*)(ws + 3498496);                 // q row-major; dead after attn
  bf16* attn = (bf16*)(ws + 3498496);                 // written by combine (after attn) 2641920
  bf16* kb   = (bf16*)(ws + 6140416);                 // k row-major 2641920
  bf16* vb   = (bf16*)(ws + 8782336);                 // v row-major 2641920
  bf16* vswz = (bf16*)(ws + 11424256);                // 3194880
  int* flag  = (int*)(ws + 14619136);                 // 256
  float* opart = (float*)(ws + 14619392);             // 21626880
  float* lpart = (float*)(ws + 36246272);             // 540672 -> total 36786944

  sniff_kernel<<<1, 256, 0, stream>>>((const unsigned short*)att, flag);
  prep_kernel<<<100 + (SEG_B + SEG_C + 255) / 256, 256, 0, stream>>>(
      x, att, Wq, Wk, Wv, Wo, Wqt, Wkt, Wvt, Wot, xbf, awA, bwB, flag);
  dim3 g1(65, 15);
  gemm_qkv<<<g1, 256, 0, stream>>>(xbf, Wqt, Wkt, Wvt, qb, kb, vb);
  swz_kernel<<<(KUNITS + VUNITS + 255) / 256, 256, 0, stream>>>(kb, vb, kswz, vswz);
  attn_kernel<<<65 * SPLITS * 8, 256, 0, stream>>>(qb, kswz, vswz, awA, bwB, opart, lpart);
  combine_kernel<<<(8 * N_TOK * 10 + 255) / 256, 256, 0, stream>>>(opart, lpart, attn);
  dim3 g2(65, 5);
  gemm_out<<<g2, 256, 0, stream>>>(attn, Wot, bo, d_out, flag);
}